// Round 1
// baseline (336.303 us; speedup 1.0000x reference)
//
#include <hip/hip_runtime.h>
#include <math.h>

#define LROWS 16384
#define HDIM  1024
#define MDIM  2048
#define NH    8
#define RSQRT_D 0.08838834764831844f   // 1/sqrt(128)

// ---- workspace layout (float offsets) ----
#define OFF_W     0          // w[8][2048]   (zeroed, atomic accum)
#define OFF_BETA  16384      // beta[8]      (zeroed, atomic accum)
#define OFF_Z     16392      // Z[8]         (zeroed, atomic accum)
#define OFF_Q     16400      // q[1024]
#define OFF_FEAT  17424      // feat[1024]
#define OFF_Y     18448      // y[8][2048]   (written by k4c)
#define OFF_P     34832      // p[16384][8]  softmax numerators (written by kA)
#define OFF_YBUF  165904     // ybuf[512][8][2048]  (33.6 MB, written by kB)
// memset zeroes only [0, OFF_Q) = 65.6 KB

__device__ __forceinline__ float dot4(float4 a, float4 b) {
  return a.x * b.x + a.y * b.y + a.z * b.z + a.w * b.w;
}
__device__ __forceinline__ void fma4(float4& acc, float s, float4 v) {
  acc.x = fmaf(s, v.x, acc.x); acc.y = fmaf(s, v.y, acc.y);
  acc.z = fmaf(s, v.z, acc.z); acc.w = fmaf(s, v.w, acc.w);
}
__device__ __forceinline__ void add4(float4& a, float4 v) {
  a.x += v.x; a.y += v.y; a.z += v.z; a.w += v.w;
}

// K1: q[j] = x . Wq[j,:] + bq[j];  beta[j&7] += q[j]*bk[j]   (wave per output)
__global__ __launch_bounds__(256) void k1_q(const float* __restrict__ x,
                                            const float* __restrict__ Wq,
                                            const float* __restrict__ bq,
                                            const float* __restrict__ bk,
                                            float* __restrict__ ws) {
  int tid = threadIdx.x, lane = tid & 63;
  int j = blockIdx.x * 4 + (tid >> 6);
  const float4* xr = (const float4*)x;
  const float4* wr = (const float4*)(Wq + (size_t)j * HDIM);
  float acc = 0.f;
#pragma unroll
  for (int i = 0; i < 4; ++i) {
    int idx = i * 64 + lane;
    acc += dot4(xr[idx], wr[idx]);
  }
#pragma unroll
  for (int off = 32; off; off >>= 1) acc += __shfl_xor(acc, off);
  if (lane == 0) {
    float qj = acc + bq[j];
    ws[OFF_Q + j] = qj;
    atomicAdd(&ws[OFF_BETA + (j & 7)], qj * bk[j]);
  }
}

// K2: w[n][m] = sum_{c: c%8==n} q[c] * Wk[c][m]   (c-chunked, atomic accum)
__global__ __launch_bounds__(256) void k2_w(const float* __restrict__ Wk,
                                            float* __restrict__ ws) {
  int tid = threadIdx.x;
  int mc = blockIdx.x & 7, cc = blockIdx.x >> 3;   // grid 128 = 8 m-chunks x 16 c-chunks
  int m = mc * 256 + tid;
  const float* q = ws + OFF_Q;
  float acc[8];
#pragma unroll
  for (int n = 0; n < 8; ++n) acc[n] = 0.f;
  int c0 = cc * 64;
  for (int c = c0; c < c0 + 64; c += 8) {
#pragma unroll
    for (int u = 0; u < 8; ++u)
      acc[u] = fmaf(q[c + u], Wk[(size_t)(c + u) * MDIM + m], acc[u]);
  }
#pragma unroll
  for (int n = 0; n < 8; ++n) atomicAdd(&ws[OFF_W + n * MDIM + m], acc[n]);
}

// KA: scores + softmax numerator only (the HBM streaming pass).
// Grid 1024 x 16 rows, 4 blocks/CU, 16 waves/CU.
// s[r][n] = (mem[r].w_n + beta_n)*d^-0.5 ; p = exp(s) (bounded |s|<~3, no max-sub)
// Writes p[r][n] to ws, atomicAdds per-block Z partials.
__global__ __launch_bounds__(256, 4) void kA_scores(const float* __restrict__ mem,
                                                    float* __restrict__ ws) {
  __shared__ float sred[4 * 32 * 33];   // 16.9 KB
  int tid = threadIdx.x, lane = tid & 63, wv = tid >> 6;
  const float* wmat = ws + OFF_W;
  int r0 = blockIdx.x * 16;

  float acc[4][8];
#pragma unroll
  for (int rr = 0; rr < 4; ++rr)
#pragma unroll
    for (int n = 0; n < 8; ++n) acc[rr][n] = 0.f;

  for (int step = 0; step < 8; ++step) {
    int mq = step * 64 + lane;
    // issue the HBM loads first (longest latency)
    float4 mv[4];
#pragma unroll
    for (int rr = 0; rr < 4; ++rr)
      mv[rr] = *(const float4*)(mem + (size_t)(r0 + wv * 4 + rr) * MDIM + mq * 4);
    // w is L2-hot (64 KB, read by every block)
    float4 wvv[8];
#pragma unroll
    for (int n = 0; n < 8; ++n)
      wvv[n] = *(const float4*)(wmat + n * MDIM + mq * 4);
#pragma unroll
    for (int rr = 0; rr < 4; ++rr) {
#pragma unroll
      for (int n = 0; n < 8; ++n) {
        acc[rr][n] = fmaf(mv[rr].x, wvv[n].x, acc[rr][n]);
        acc[rr][n] = fmaf(mv[rr].y, wvv[n].y, acc[rr][n]);
        acc[rr][n] = fmaf(mv[rr].z, wvv[n].z, acc[rr][n]);
        acc[rr][n] = fmaf(mv[rr].w, wvv[n].w, acc[rr][n]);
      }
    }
  }
#pragma unroll
  for (int rr = 0; rr < 4; ++rr)
#pragma unroll
    for (int n = 0; n < 8; ++n) acc[rr][n] += __shfl_xor(acc[rr][n], 32);
  if (lane < 32) {
#pragma unroll
    for (int rr = 0; rr < 4; ++rr)
#pragma unroll
      for (int n = 0; n < 8; ++n)
        sred[wv * 1056 + lane * 33 + rr * 8 + n] = acc[rr][n];
  }
  __syncthreads();
  if (tid < 128) {
    int rowl = tid >> 3, n = tid & 7;
    int wvx = rowl >> 2, rr = rowl & 3;
    const float* base = sred + wvx * 1056 + rr * 8 + n;
    float s = 0.f;
#pragma unroll
    for (int l = 0; l < 32; ++l) s += base[l * 33];
    s = (s + ws[OFF_BETA + n]) * RSQRT_D;
    float p = __expf(s);
    ws[OFF_P + (size_t)(r0 + rowl) * 8 + n] = p;
    // Z reduction: lanes {l, l^8, l^16, l^32,...} share n = l&7
    float z = p;
    z += __shfl_xor(z, 8); z += __shfl_xor(z, 16); z += __shfl_xor(z, 32);
    if ((tid & 63) < 8) atomicAdd(&ws[OFF_Z + n], z);
  }
}

// KB: y-partials, mem is L3-resident after kA.
// Grid 1024 = 512 row-chunks (32 rows) x 2 col-halves (1024 cols), 4 blocks/CU.
// Each thread owns 4 cols, accumulates acc[8] over 32 rows, writes the
// 512-slot ybuf layout k4c already reduces.
__global__ __launch_bounds__(256, 4) void kB_wsum(const float* __restrict__ mem,
                                                  float* __restrict__ ws) {
  __shared__ float pp[32 * 8];   // p for this row chunk, 1 KB
  int tid = threadIdx.x;
  int rc = blockIdx.x >> 1, ch = blockIdx.x & 1;
  int r0 = rc * 32;
  pp[tid] = ws[OFF_P + (size_t)r0 * 8 + tid];
  __syncthreads();

  float4 acc[8];
#pragma unroll
  for (int n = 0; n < 8; ++n) acc[n] = make_float4(0.f, 0.f, 0.f, 0.f);

  const float* base = mem + (size_t)r0 * MDIM + ch * 1024 + tid * 4;
#pragma unroll 4
  for (int r = 0; r < 32; ++r) {
    float4 mv = *(const float4*)(base + (size_t)r * MDIM);
    float4 pA = *(const float4*)(pp + r * 8);       // broadcast
    float4 pB = *(const float4*)(pp + r * 8 + 4);   // broadcast
    fma4(acc[0], pA.x, mv); fma4(acc[1], pA.y, mv);
    fma4(acc[2], pA.z, mv); fma4(acc[3], pA.w, mv);
    fma4(acc[4], pB.x, mv); fma4(acc[5], pB.y, mv);
    fma4(acc[6], pB.z, mv); fma4(acc[7], pB.w, mv);
  }
  float* yb = ws + OFF_YBUF + (size_t)rc * 16384 + ch * 1024 + tid * 4;
#pragma unroll
  for (int n = 0; n < 8; ++n)
    *(float4*)(yb + n * MDIM) = acc[n];
}

// K4c: y[q] = sum_{b=0..511} ybuf[b][q]   (q = float4 index, 4096 total)
__global__ __launch_bounds__(256) void k4c(float* __restrict__ ws) {
  __shared__ float4 sA[256];
  int t = threadIdx.x;
  int quad = blockIdx.x * 16 + (t & 15);
  int b0 = (t >> 4) * 32;
  const float4* src = (const float4*)(ws + OFF_YBUF);
  float4 acc = make_float4(0.f, 0.f, 0.f, 0.f);
  for (int b = b0; b < b0 + 32; ++b)
    add4(acc, src[(size_t)b * 4096 + quad]);
  sA[(t & 15) * 16 + (t >> 4)] = acc;
  __syncthreads();
  if (t < 16) {
    float4 s = sA[t * 16];
#pragma unroll
    for (int j = 1; j < 16; ++j) add4(s, sA[t * 16 + j]);
    ((float4*)(ws + OFF_Y))[blockIdx.x * 16 + t] = s;
  }
}

// K6: feat[c] = (y[c&7] . Wv[c,:]) / Z[c&7] + bv[c]   (wave per c)
__global__ __launch_bounds__(256) void k6_feat(const float* __restrict__ Wv,
                                               const float* __restrict__ bv,
                                               float* __restrict__ ws) {
  int tid = threadIdx.x, lane = tid & 63;
  int c = blockIdx.x * 4 + (tid >> 6);
  int n = c & 7;
  const float4* yb = (const float4*)(ws + OFF_Y + n * MDIM);
  const float4* wb = (const float4*)(Wv + (size_t)c * MDIM);
  float acc = 0.f;
#pragma unroll
  for (int s = 0; s < 8; ++s) {
    int idx = s * 64 + lane;
    acc += dot4(yb[idx], wb[idx]);
  }
#pragma unroll
  for (int off = 32; off; off >>= 1) acc += __shfl_xor(acc, off);
  if (lane == 0) ws[OFF_FEAT + c] = acc / ws[OFF_Z + n] + bv[c];
}

// K7: out[j] = relu(x . Wo[j,0:1024] + feat . Wo[j,1024:2048] + bo[j]) (wave per j)
__global__ __launch_bounds__(256) void k7_out(const float* __restrict__ x,
                                              const float* __restrict__ Wo,
                                              const float* __restrict__ bo,
                                              const float* __restrict__ ws,
                                              float* __restrict__ out) {
  int tid = threadIdx.x, lane = tid & 63;
  int j = blockIdx.x * 4 + (tid >> 6);
  const float4* wb = (const float4*)(Wo + (size_t)j * 2048);
  const float4* xr = (const float4*)x;
  const float4* fr = (const float4*)(ws + OFF_FEAT);
  float acc = 0.f;
#pragma unroll
  for (int s = 0; s < 4; ++s) {
    int idx = s * 64 + lane;
    acc += dot4(xr[idx], wb[idx]);
    acc += dot4(fr[idx], wb[256 + idx]);
  }
#pragma unroll
  for (int off = 32; off; off >>= 1) acc += __shfl_xor(acc, off);
  if (lane == 0) out[j] = fmaxf(acc + bo[j], 0.f);
}

extern "C" void kernel_launch(void* const* d_in, const int* in_sizes, int n_in,
                              void* d_out, int out_size, void* d_ws, size_t ws_size,
                              hipStream_t stream) {
  const float* x   = (const float*)d_in[0];
  const float* mem = (const float*)d_in[1];
  const float* Wq  = (const float*)d_in[2];
  const float* bq  = (const float*)d_in[3];
  const float* Wk  = (const float*)d_in[4];
  const float* bk  = (const float*)d_in[5];
  const float* Wv  = (const float*)d_in[6];
  const float* bv  = (const float*)d_in[7];
  const float* Wo  = (const float*)d_in[8];
  const float* bo  = (const float*)d_in[9];
  float* ws  = (float*)d_ws;
  float* out = (float*)d_out;

  // zero w, beta, Z (65.6 KB)
  hipMemsetAsync(ws, 0, OFF_Q * sizeof(float), stream);

  k1_q    <<<256, 256, 0, stream>>>(x, Wq, bq, bk, ws);
  k2_w    <<<128, 256, 0, stream>>>(Wk, ws);
  kA_scores<<<1024, 256, 0, stream>>>(mem, ws);
  kB_wsum <<<1024, 256, 0, stream>>>(mem, ws);
  k4c     <<<256, 256, 0, stream>>>(ws);
  k6_feat <<<256, 256, 0, stream>>>(Wv, bv, ws);
  k7_out  <<<256, 256, 0, stream>>>(x, Wo, bo, ws, out);
}

// Round 2
// 289.044 us; speedup vs baseline: 1.1635x; 1.1635x over previous
//
#include <hip/hip_runtime.h>
#include <math.h>

#define LROWS 16384
#define HDIM  1024
#define MDIM  2048
#define NH    8
#define RSQRT_D 0.08838834764831844f   // 1/sqrt(128)

// ---- workspace layout (float offsets) ----
#define OFF_W     0          // w[8][2048]   (zeroed, atomic accum)
#define OFF_BETA  16384      // beta[8]      (zeroed, atomic accum)
#define OFF_Z     16392      // Z[8]         (zeroed, atomic accum)
#define OFF_Q     16400      // q[1024]
#define OFF_FEAT  17424      // feat[1024]
#define OFF_Y     18448      // y[8][2048]   (written by k4c)
#define OFF_S2    34832      // s2[2][16384][8] partial scores (1 MB, fully written)
#define OFF_YBUF  296976     // ybuf[512][8][2048]  (33.6 MB, written by kB)
// memset zeroes only [0, OFF_Q) = 65.6 KB

__device__ __forceinline__ float dot4(float4 a, float4 b) {
  return a.x * b.x + a.y * b.y + a.z * b.z + a.w * b.w;
}
__device__ __forceinline__ void fma4(float4& acc, float s, float4 v) {
  acc.x = fmaf(s, v.x, acc.x); acc.y = fmaf(s, v.y, acc.y);
  acc.z = fmaf(s, v.z, acc.z); acc.w = fmaf(s, v.w, acc.w);
}
__device__ __forceinline__ void add4(float4& a, float4 v) {
  a.x += v.x; a.y += v.y; a.z += v.z; a.w += v.w;
}

// K1: q[j] = x . Wq[j,:] + bq[j];  beta[j&7] += q[j]*bk[j]   (wave per output)
__global__ __launch_bounds__(256) void k1_q(const float* __restrict__ x,
                                            const float* __restrict__ Wq,
                                            const float* __restrict__ bq,
                                            const float* __restrict__ bk,
                                            float* __restrict__ ws) {
  int tid = threadIdx.x, lane = tid & 63;
  int j = blockIdx.x * 4 + (tid >> 6);
  const float4* xr = (const float4*)x;
  const float4* wr = (const float4*)(Wq + (size_t)j * HDIM);
  float acc = 0.f;
#pragma unroll
  for (int i = 0; i < 4; ++i) {
    int idx = i * 64 + lane;
    acc += dot4(xr[idx], wr[idx]);
  }
#pragma unroll
  for (int off = 32; off; off >>= 1) acc += __shfl_xor(acc, off);
  if (lane == 0) {
    float qj = acc + bq[j];
    ws[OFF_Q + j] = qj;
    atomicAdd(&ws[OFF_BETA + (j & 7)], qj * bk[j]);
  }
}

// K2: w[n][m] = sum_{c: c%8==n} q[c] * Wk[c][m]
// grid 256 = 8 m-chunks x 32 c-chunks (32 c each), fully-unrolled 32-load body.
__global__ __launch_bounds__(256) void k2_w(const float* __restrict__ Wk,
                                            float* __restrict__ ws) {
  int tid = threadIdx.x;
  int mc = blockIdx.x & 7, cc = blockIdx.x >> 3;
  int m = mc * 256 + tid;
  const float* q = ws + OFF_Q;
  float acc[8];
#pragma unroll
  for (int n = 0; n < 8; ++n) acc[n] = 0.f;
  int c0 = cc * 32;
#pragma unroll
  for (int cb = 0; cb < 32; cb += 8) {
#pragma unroll
    for (int u = 0; u < 8; ++u)
      acc[u] = fmaf(q[c0 + cb + u], Wk[(size_t)(c0 + cb + u) * MDIM + m], acc[u]);
  }
#pragma unroll
  for (int n = 0; n < 8; ++n) atomicAdd(&ws[OFF_W + n * MDIM + m], acc[n]);
}

// KA2: partial scores, kB-shaped inner loop.
// Grid 2048 = 1024 row-groups (16 rows) x 2 col-halves (1024 cols).
// w half staged in LDS (32 KB); inner step = 4 mem float4 (prefetched) +
// 8 ds_read_b128 + 128 FMA. Per-wave 64-lane butterfly reduce; lane0 writes
// s2[ch][r][n] partials (no atomics).
__global__ __launch_bounds__(256, 4) void kA2(const float* __restrict__ mem,
                                              float* __restrict__ ws) {
  __shared__ float4 wlds[2048];   // w[n][c4], 32 KB
  int tid = threadIdx.x, lane = tid & 63, wv = tid >> 6;
  int rg = blockIdx.x >> 1, ch = blockIdx.x & 1;
  int r0 = rg * 16;

  // stage w column-half into LDS (coalesced)
  const float4* wsrc = (const float4*)(ws + OFF_W + ch * 1024);
#pragma unroll
  for (int k = 0; k < 8; ++k) {
    int qi = k * 256 + tid;            // qi = n*256 + c4
    int n = qi >> 8, c4 = qi & 255;
    wlds[qi] = wsrc[n * 512 + c4];     // row stride 2048 floats = 512 float4
  }
  __syncthreads();

  float acc[4][8];
#pragma unroll
  for (int rr = 0; rr < 4; ++rr)
#pragma unroll
    for (int n = 0; n < 8; ++n) acc[rr][n] = 0.f;

  const size_t cbase = (size_t)ch * 1024;
  float4 mv[4], mvn[4];
#pragma unroll
  for (int rr = 0; rr < 4; ++rr)
    mv[rr] = *(const float4*)(mem + (size_t)(r0 + wv * 4 + rr) * MDIM + cbase + (size_t)lane * 4);

#pragma unroll
  for (int step = 0; step < 4; ++step) {
    int cq = step * 64 + lane;
    float4 wvv[8];
#pragma unroll
    for (int n = 0; n < 8; ++n) wvv[n] = wlds[n * 256 + cq];
    if (step < 3) {
#pragma unroll
      for (int rr = 0; rr < 4; ++rr)
        mvn[rr] = *(const float4*)(mem + (size_t)(r0 + wv * 4 + rr) * MDIM + cbase + (size_t)(cq + 64) * 4);
    }
#pragma unroll
    for (int rr = 0; rr < 4; ++rr) {
#pragma unroll
      for (int n = 0; n < 8; ++n) {
        acc[rr][n] = fmaf(mv[rr].x, wvv[n].x, acc[rr][n]);
        acc[rr][n] = fmaf(mv[rr].y, wvv[n].y, acc[rr][n]);
        acc[rr][n] = fmaf(mv[rr].z, wvv[n].z, acc[rr][n]);
        acc[rr][n] = fmaf(mv[rr].w, wvv[n].w, acc[rr][n]);
      }
    }
#pragma unroll
    for (int rr = 0; rr < 4; ++rr) mv[rr] = mvn[rr];
  }

  // 64-lane butterfly: every lane ends with the full half-column sums
#pragma unroll
  for (int off = 1; off < 64; off <<= 1) {
#pragma unroll
    for (int rr = 0; rr < 4; ++rr)
#pragma unroll
      for (int n = 0; n < 8; ++n)
        acc[rr][n] += __shfl_xor(acc[rr][n], off);
  }
  if (lane == 0) {
    float* sdst = ws + OFF_S2 + (size_t)ch * 131072 + (size_t)(r0 + wv * 4) * 8;
#pragma unroll
    for (int rr = 0; rr < 4; ++rr)
#pragma unroll
      for (int n = 0; n < 8; ++n)
        sdst[rr * 8 + n] = acc[rr][n];   // 32 consecutive floats (2 lines)
  }
}

// KB2: combine score halves -> p = exp((s+beta)*rsqrtd), Z partials (ch0),
// then the proven kB weighted-sum loop (mem L3-hot after kA2).
// Grid 1024 = 512 row-chunks (32 rows) x 2 col-halves.
__global__ __launch_bounds__(256, 4) void kB2(const float* __restrict__ mem,
                                              float* __restrict__ ws) {
  __shared__ __align__(16) float pp[256];  // p[32 rows][8 heads]
  __shared__ float zz[32];
  int tid = threadIdx.x;
  int rc = blockIdx.x >> 1, ch = blockIdx.x & 1;
  int r0 = rc * 32;
  {
    int n = tid & 7;
    int r = r0 + (tid >> 3);
    float s0 = ws[OFF_S2 + (size_t)r * 8 + n];
    float s1 = ws[OFF_S2 + 131072 + (size_t)r * 8 + n];
    float p = __expf((s0 + s1 + ws[OFF_BETA + n]) * RSQRT_D);
    pp[tid] = p;
    if (ch == 0) {
      float z = p;
      z += __shfl_xor(z, 8); z += __shfl_xor(z, 16); z += __shfl_xor(z, 32);
      if ((tid & 63) < 8) zz[(tid >> 6) * 8 + n] = z;
    }
  }
  __syncthreads();
  if (ch == 0 && tid < 8)
    atomicAdd(&ws[OFF_Z + tid], zz[tid] + zz[8 + tid] + zz[16 + tid] + zz[24 + tid]);

  float4 acc[8];
#pragma unroll
  for (int n = 0; n < 8; ++n) acc[n] = make_float4(0.f, 0.f, 0.f, 0.f);

  const float* base = mem + (size_t)r0 * MDIM + ch * 1024 + tid * 4;
#pragma unroll 4
  for (int r = 0; r < 32; ++r) {
    float4 mv = *(const float4*)(base + (size_t)r * MDIM);
    float4 pA = *(const float4*)(pp + r * 8);       // broadcast
    float4 pB = *(const float4*)(pp + r * 8 + 4);   // broadcast
    fma4(acc[0], pA.x, mv); fma4(acc[1], pA.y, mv);
    fma4(acc[2], pA.z, mv); fma4(acc[3], pA.w, mv);
    fma4(acc[4], pB.x, mv); fma4(acc[5], pB.y, mv);
    fma4(acc[6], pB.z, mv); fma4(acc[7], pB.w, mv);
  }
  float* yb = ws + OFF_YBUF + (size_t)rc * 16384 + ch * 1024 + tid * 4;
#pragma unroll
  for (int n = 0; n < 8; ++n)
    *(float4*)(yb + n * MDIM) = acc[n];
}

// K4c: y[q] = sum_{b=0..511} ybuf[b][q]   (q = float4 index, 4096 total)
__global__ __launch_bounds__(256) void k4c(float* __restrict__ ws) {
  __shared__ float4 sA[256];
  int t = threadIdx.x;
  int quad = blockIdx.x * 16 + (t & 15);
  int b0 = (t >> 4) * 32;
  const float4* src = (const float4*)(ws + OFF_YBUF);
  float4 acc = make_float4(0.f, 0.f, 0.f, 0.f);
  for (int b = b0; b < b0 + 32; ++b)
    add4(acc, src[(size_t)b * 4096 + quad]);
  sA[(t & 15) * 16 + (t >> 4)] = acc;
  __syncthreads();
  if (t < 16) {
    float4 s = sA[t * 16];
#pragma unroll
    for (int j = 1; j < 16; ++j) add4(s, sA[t * 16 + j]);
    ((float4*)(ws + OFF_Y))[blockIdx.x * 16 + t] = s;
  }
}

// K6: feat[c] = (y[c&7] . Wv[c,:]) / Z[c&7] + bv[c]   (wave per c)
__global__ __launch_bounds__(256) void k6_feat(const float* __restrict__ Wv,
                                               const float* __restrict__ bv,
                                               float* __restrict__ ws) {
  int tid = threadIdx.x, lane = tid & 63;
  int c = blockIdx.x * 4 + (tid >> 6);
  int n = c & 7;
  const float4* yb = (const float4*)(ws + OFF_Y + n * MDIM);
  const float4* wb = (const float4*)(Wv + (size_t)c * MDIM);
  float acc = 0.f;
#pragma unroll
  for (int s = 0; s < 8; ++s) {
    int idx = s * 64 + lane;
    acc += dot4(yb[idx], wb[idx]);
  }
#pragma unroll
  for (int off = 32; off; off >>= 1) acc += __shfl_xor(acc, off);
  if (lane == 0) ws[OFF_FEAT + c] = acc / ws[OFF_Z + n] + bv[c];
}

// K7: out[j] = relu(x . Wo[j,0:1024] + feat . Wo[j,1024:2048] + bo[j]) (wave per j)
__global__ __launch_bounds__(256) void k7_out(const float* __restrict__ x,
                                              const float* __restrict__ Wo,
                                              const float* __restrict__ bo,
                                              const float* __restrict__ ws,
                                              float* __restrict__ out) {
  int tid = threadIdx.x, lane = tid & 63;
  int j = blockIdx.x * 4 + (tid >> 6);
  const float4* wb = (const float4*)(Wo + (size_t)j * 2048);
  const float4* xr = (const float4*)x;
  const float4* fr = (const float4*)(ws + OFF_FEAT);
  float acc = 0.f;
#pragma unroll
  for (int s = 0; s < 4; ++s) {
    int idx = s * 64 + lane;
    acc += dot4(xr[idx], wb[idx]);
    acc += dot4(fr[idx], wb[256 + idx]);
  }
#pragma unroll
  for (int off = 32; off; off >>= 1) acc += __shfl_xor(acc, off);
  if (lane == 0) out[j] = fmaxf(acc + bo[j], 0.f);
}

extern "C" void kernel_launch(void* const* d_in, const int* in_sizes, int n_in,
                              void* d_out, int out_size, void* d_ws, size_t ws_size,
                              hipStream_t stream) {
  const float* x   = (const float*)d_in[0];
  const float* mem = (const float*)d_in[1];
  const float* Wq  = (const float*)d_in[2];
  const float* bq  = (const float*)d_in[3];
  const float* Wk  = (const float*)d_in[4];
  const float* bk  = (const float*)d_in[5];
  const float* Wv  = (const float*)d_in[6];
  const float* bv  = (const float*)d_in[7];
  const float* Wo  = (const float*)d_in[8];
  const float* bo  = (const float*)d_in[9];
  float* ws  = (float*)d_ws;
  float* out = (float*)d_out;

  // zero w, beta, Z (65.6 KB)
  hipMemsetAsync(ws, 0, OFF_Q * sizeof(float), stream);

  k1_q   <<<256, 256, 0, stream>>>(x, Wq, bq, bk, ws);
  k2_w   <<<256, 256, 0, stream>>>(Wk, ws);
  kA2    <<<2048, 256, 0, stream>>>(mem, ws);
  kB2    <<<1024, 256, 0, stream>>>(mem, ws);
  k4c    <<<256, 256, 0, stream>>>(ws);
  k6_feat<<<256, 256, 0, stream>>>(Wv, bv, ws);
  k7_out <<<256, 256, 0, stream>>>(x, Wo, bo, ws, out);
}